// Round 6
// baseline (1461.750 us; speedup 1.0000x reference)
//
#include <hip/hip_runtime.h>
#include <hip/hip_bf16.h>
#include <math.h>

typedef unsigned short u16;
typedef unsigned int   u32;

#define PI_F 3.14159265358979323846f

__device__ __forceinline__ float bf2f(u16 u) {
  union { u32 i; float f; } v; v.i = ((u32)u) << 16; return v.f;
}
__device__ __forceinline__ u16 f2bf(float f) {
  union { float f; u32 i; } v; v.f = f;
  u32 x = v.i;
  return (u16)((x + 0x7fffu + ((x >> 16) & 1u)) >> 16);  // RNE
}
__device__ __forceinline__ float lo16f(u32 u) { return bf2f((u16)(u & 0xffffu)); }
__device__ __forceinline__ float hi16f(u32 u) { return bf2f((u16)(u >> 16)); }

// ---- dtype-agnostic input loads (isbf is wave-uniform) ---------------------
__device__ __forceinline__ float lds1(const void* p, size_t i, int isbf) {
  return isbf ? bf2f(((const u16*)p)[i]) : ((const float*)p)[i];
}
__device__ __forceinline__ float4 ld4(const void* p, size_t i, int isbf) {
  if (isbf) {
    uint2 u = *(const uint2*)((const u16*)p + i);
    return make_float4(lo16f(u.x), hi16f(u.x), lo16f(u.y), hi16f(u.y));
  }
  return *(const float4*)((const float*)p + i);
}
__device__ __forceinline__ void ld8(const void* p, size_t i, int isbf, float* dst) {
  if (isbf) {
    uint4 u = *(const uint4*)((const u16*)p + i);
    dst[0]=lo16f(u.x); dst[1]=hi16f(u.x); dst[2]=lo16f(u.y); dst[3]=hi16f(u.y);
    dst[4]=lo16f(u.z); dst[5]=hi16f(u.z); dst[6]=lo16f(u.w); dst[7]=hi16f(u.w);
  } else {
    float4 a = *(const float4*)((const float*)p + i);
    float4 b = *(const float4*)((const float*)p + i + 4);
    dst[0]=a.x; dst[1]=a.y; dst[2]=a.z; dst[3]=a.w;
    dst[4]=b.x; dst[5]=b.y; dst[6]=b.z; dst[7]=b.w;
  }
}

__device__ __forceinline__ float2 cmulf(float2 a, float c, float s) {
  return make_float2(a.x*c - a.y*s, a.x*s + a.y*c);
}

// ---------------------------------------------------------------------------
// Kernel 0: dtype detect. Even-indexed u16s of x: bf16 data -> exponent field
// is N(0,1)-plausible (~100%); float32 data -> low mantissa halves (~14%).
// ---------------------------------------------------------------------------
__global__ __launch_bounds__(64) void k_detect(const u16* __restrict__ x,
                                               u32* __restrict__ flag) {
  __shared__ int cnt[64];
  const int lane = threadIdx.x;
  int c = 0;
  for (int i = 0; i < 16; ++i) {
    u32 u = x[(size_t)(lane * 16 + i) * 1024];   // even u16 index, < 1.05M
    int e = (u >> 7) & 0xFF;
    c += (e >= 0x60 && e < 0x84) ? 1 : 0;
  }
  cnt[lane] = c;
  __syncthreads();
  if (lane == 0) {
    int s = 0;
    for (int i = 0; i < 64; ++i) s += cnt[i];
    *flag = (s > 512) ? 1u : 0u;
  }
}

// ---------------------------------------------------------------------------
// 256-point complex FFT, radix-4 Stockham, 64 lanes per FFT (lane = j).
// Data starts in b0, ends in b0 (4 stages, ping-pong). DIR=-1 fwd, +1 inv.
// ---------------------------------------------------------------------------
template<int DIR>
__device__ void fft256(float2* b0, float2* b1, int lane) {
  float2* src = b0;
  float2* dst = b1;
#pragma unroll
  for (int Ns = 1; Ns < 256; Ns *= 4) {
    int jm = lane & (Ns - 1);
    float ang = (float)DIR * (2.0f * PI_F) * (float)jm / (float)(Ns * 4);
    float2 v0 = src[lane];
    float2 v1 = src[lane + 64];
    float2 v2 = src[lane + 128];
    float2 v3 = src[lane + 192];
    float s1, c1;
    __sincosf(ang, &s1, &c1);
    float c2 = c1*c1 - s1*s1, s2 = 2.f*c1*s1;
    float c3 = c2*c1 - s2*s1, s3 = s2*c1 + c2*s1;
    v1 = cmulf(v1, c1, s1);
    v2 = cmulf(v2, c2, s2);
    v3 = cmulf(v3, c3, s3);
    float2 t0 = make_float2(v0.x + v2.x, v0.y + v2.y);
    float2 t1 = make_float2(v0.x - v2.x, v0.y - v2.y);
    float2 t2 = make_float2(v1.x + v3.x, v1.y + v3.y);
    float2 t3 = make_float2(v1.x - v3.x, v1.y - v3.y);
    float2 t3r = (DIR < 0) ? make_float2(t3.y, -t3.x) : make_float2(-t3.y, t3.x);
    int idxD = (lane / Ns) * (Ns * 4) + jm;
    dst[idxD]          = make_float2(t0.x + t2.x, t0.y + t2.y);
    dst[idxD + Ns]     = make_float2(t1.x + t3r.x, t1.y + t3r.y);
    dst[idxD + 2 * Ns] = make_float2(t0.x - t2.x, t0.y - t2.y);
    dst[idxD + 3 * Ns] = make_float2(t1.x - t3r.x, t1.y - t3r.y);
    float2* tmp = src; src = dst; dst = tmp;
    __syncthreads();
  }
}

// ---------------------------------------------------------------------------
// Kernel 1: window attention (local mixer). ONE BLOCK PER WINDOW.
// Thread = (head wv = tid>>6, token lane = tid&63).
//
// v2: weights/bias are read straight from GLOBAL with wave-uniform addresses
// (wv via readfirstlane -> divergence analysis proves uniformity -> s_load
// into SGPRs; v_fma takes one SGPR operand). This removes the 12KB wl LDS
// staging AND ~192 uniform ds_read_b128/wave that serialized on the per-CU
// LDS pipe (R5 diagnosis: LDS-pipe-bound, VALUBusy only ~14%). LDS is now
// just qkv[96][64] = 24KB -> 6 blocks/CU.
// ---------------------------------------------------------------------------
__global__ __launch_bounds__(256) void k_attn(
    const void* __restrict__ x, const void* __restrict__ wqkv,
    const void* __restrict__ bqkv, const void* __restrict__ pos,
    u16* __restrict__ cat1, const u32* __restrict__ flag) {
  __shared__ __align__(16) float qkv[96 * 64];    // 24 KB: row d, col token

  const int isbf = (int)*flag;
  const int tid = threadIdx.x;
  const int wv = __builtin_amdgcn_readfirstlane(tid >> 6);  // uniform wave id
  const int lane = tid & 63;   // token = i0*8+j0

  const int w = blockIdx.x;    // window id 0..8191
  const int b = w >> 10;
  const int rem = w & 1023;
  const int by = rem >> 5, bx = rem & 31;
  const int i0 = lane >> 3, j0 = lane & 7;
  const int py = by * 8 + i0, px = bx * 8 + j0;

  // token's 32 input channels (first half of c=64)
  const size_t pixbase = ((size_t)((b * 256 + py) * 256 + px)) * 64;
  float xr[32];
#pragma unroll
  for (int g = 0; g < 4; ++g) ld8(x, pixbase + g * 8, isbf, xr + g * 8);

  // ---- QKV: wave wv computes output rows d in [wv*24, wv*24+24) ----------
  // weight/bias reads: uniform global -> s_load (scalar pipe, no LDS)
#pragma unroll
  for (int dd0 = 0; dd0 < 24; dd0 += 8) {
    const int d0 = wv * 24 + dd0;
    float acc[8];
#pragma unroll
    for (int u = 0; u < 8; ++u) acc[u] = lds1(bqkv, d0 + u, isbf);
#pragma unroll
    for (int u = 0; u < 8; ++u) {
#pragma unroll
      for (int cb = 0; cb < 8; ++cb) {
        float4 w4 = ld4(wqkv, (size_t)(d0 + u) * 32 + cb * 4, isbf);
        acc[u] = fmaf(xr[cb*4+0], w4.x, acc[u]);
        acc[u] = fmaf(xr[cb*4+1], w4.y, acc[u]);
        acc[u] = fmaf(xr[cb*4+2], w4.z, acc[u]);
        acc[u] = fmaf(xr[cb*4+3], w4.w, acc[u]);
      }
    }
#pragma unroll
    for (int u = 0; u < 8; ++u) qkv[(d0 + u) * 64 + lane] = acc[u];  // stride-1
  }
  __syncthreads();

  // ---- attention: this thread owns (head wv, query token lane) -----------
  float qv[8];
#pragma unroll
  for (int cc = 0; cc < 8; ++cc)
    qv[cc] = qkv[(wv * 8 + cc) * 64 + lane] * 0.35355339059327373f;
  const float* kt = qkv + (32 + wv * 8) * 64;   // k rows for this head
  const float* vt = qkv + (64 + wv * 8) * 64;   // v rows for this head

  float m = -1e30f, l = 0.f;
  float o[8];
#pragma unroll
  for (int cc = 0; cc < 8; ++cc) o[cc] = 0.f;
  const size_t prow = (size_t)(wv * 64 + lane) * 64;

#pragma unroll 1
  for (int jb = 0; jb < 16; ++jb) {
    float4 pp = ld4(pos, prow + jb * 4, isbf);
    float s0 = pp.x, s1 = pp.y, s2 = pp.z, s3 = pp.w;
#pragma unroll
    for (int cc = 0; cc < 8; ++cc) {
      float4 k4 = *(const float4*)(kt + cc * 64 + jb * 4);   // uniform: bcast
      float q1 = qv[cc];
      s0 = fmaf(q1, k4.x, s0); s1 = fmaf(q1, k4.y, s1);
      s2 = fmaf(q1, k4.z, s2); s3 = fmaf(q1, k4.w, s3);
    }
    float mn = fmaxf(fmaxf(fmaxf(s0, s1), fmaxf(s2, s3)), m);
    float fac = __expf(m - mn);
    float e0 = __expf(s0 - mn), e1 = __expf(s1 - mn);
    float e2 = __expf(s2 - mn), e3 = __expf(s3 - mn);
    l = l * fac + (e0 + e1 + e2 + e3);
#pragma unroll
    for (int cc = 0; cc < 8; ++cc) {
      float4 v4 = *(const float4*)(vt + cc * 64 + jb * 4);   // uniform: bcast
      float t = o[cc] * fac;
      t = fmaf(e0, v4.x, t); t = fmaf(e1, v4.y, t);
      t = fmaf(e2, v4.z, t); t = fmaf(e3, v4.w, t);
      o[cc] = t;
    }
    m = mn;
  }
  float rs = 1.f / l;

  // head wv owns channels wv*8..wv*8+7 of pixel (py,px): one 16B store
  u16* opix = cat1 + ((size_t)((b * 256 + py) * 256 + px)) * 32 + wv * 8;
  uint4 u;
  u.x = (u32)f2bf(o[0] * rs) | ((u32)f2bf(o[1] * rs) << 16);
  u.y = (u32)f2bf(o[2] * rs) | ((u32)f2bf(o[3] * rs) << 16);
  u.z = (u32)f2bf(o[4] * rs) | ((u32)f2bf(o[5] * rs) << 16);
  u.w = (u32)f2bf(o[6] * rs) | ((u32)f2bf(o[7] * rs) << 16);
  *(uint4*)opix = u;
}

// ---------------------------------------------------------------------------
// Kernel 2: forward row FFTs (along w). Block = one (b,y); wave per channel
// iter. temp layout: [b*32+c][y][132] float2, k=0..128 valid.
// ---------------------------------------------------------------------------
__global__ __launch_bounds__(256) void k_fft_rows(
    const void* __restrict__ x, float2* __restrict__ temp,
    const u32* __restrict__ flag) {
  __shared__ __align__(16) float2 buf[4][2][256];
  const int isbf = (int)*flag;
  const int tid = threadIdx.x, wv = tid >> 6, lane = tid & 63;
  const int bid = blockIdx.x;
  const int b = bid >> 8, y = bid & 255;
  const size_t rowbase = (size_t)(b * 256 + y) * 256 * 64;

  for (int it = 0; it < 8; ++it) {
    const int c = it * 4 + wv;
#pragma unroll
    for (int r = 0; r < 4; ++r) {
      int xc = lane + 64 * r;
      float v = lds1(x, rowbase + (size_t)xc * 64 + 32 + c, isbf);
      buf[wv][0][xc] = make_float2(v, 0.f);
    }
    __syncthreads();
    fft256<-1>(&buf[wv][0][0], &buf[wv][1][0], lane);
    float2* row = temp + ((size_t)(b * 32 + c) * 256 + y) * 132;
    row[lane]      = buf[wv][0][lane];
    row[lane + 64] = buf[wv][0][lane + 64];
    if (lane == 0) row[128] = buf[wv][0][128];
    __syncthreads();
  }
}

// ---------------------------------------------------------------------------
// Kernel 3: column FFT + amp/phase pointwise + inverse column FFT.
// Block = (plane p = b*32+c, tile of 4 kx columns). 33 tiles.
// ---------------------------------------------------------------------------
__global__ __launch_bounds__(256) void k_fft_cols(
    float2* __restrict__ temp,
    const void* __restrict__ aw, const void* __restrict__ ab,
    const void* __restrict__ pw, const void* __restrict__ pb,
    const u32* __restrict__ flag) {
  __shared__ __align__(16) float2 cb[4][2][256];
  const int isbf = (int)*flag;
  const int tid = threadIdx.x, wv = tid >> 6, lane = tid & 63;
  const int tile = blockIdx.x % 33;
  const int p = blockIdx.x / 33;
  const int c = p & 31;
  const int k0 = tile * 4;
  float2* plane = temp + (size_t)p * 256 * 132;

  {
    const int y = tid;
    const float4* src = (const float4*)(plane + (size_t)y * 132 + k0);
    float4 f0 = src[0], f1 = src[1];
    cb[0][0][y] = make_float2(f0.x, f0.y);
    cb[1][0][y] = make_float2(f0.z, f0.w);
    cb[2][0][y] = make_float2(f1.x, f1.y);
    cb[3][0][y] = make_float2(f1.z, f1.w);
  }
  __syncthreads();
  fft256<-1>(&cb[wv][0][0], &cb[wv][1][0], lane);

  const float awf = lds1(aw, c, isbf), abf = lds1(ab, c, isbf);
  const float pwf = lds1(pw, c, isbf), pbf = lds1(pb, c, isbf);
#pragma unroll
  for (int r = 0; r < 4; ++r) {
    float2 F = cb[wv][0][lane + 64 * r];
    float amp = sqrtf(F.x * F.x + F.y * F.y);
    float ph = atan2f(F.y, F.x);
    float a2 = amp * awf + abf;
    float p2 = ph * pwf + pbf;
    float sn, cs;
    __sincosf(p2, &sn, &cs);
    cb[wv][0][lane + 64 * r] = make_float2(a2 * cs + 2e-8f, a2 * sn + 1e-8f);
  }
  __syncthreads();
  fft256<1>(&cb[wv][0][0], &cb[wv][1][0], lane);
  // trailing barrier inside fft256 makes cross-wave reads below safe
  {
    const int y = tid;
    float4* dst = (float4*)(plane + (size_t)y * 132 + k0);
    float2 a0 = cb[0][0][y], a1 = cb[1][0][y], a2 = cb[2][0][y], a3 = cb[3][0][y];
    dst[0] = make_float4(a0.x, a0.y, a1.x, a1.y);
    dst[1] = make_float4(a2.x, a2.y, a3.x, a3.y);
  }
}

// ---------------------------------------------------------------------------
// Kernel 4: inverse row FFTs (Hermitian reconstruct), *1/65536, abs,
// write x2 bf16 to cat2 [b,y,x,32] via LDS slab (coalesced).
// ---------------------------------------------------------------------------
__global__ __launch_bounds__(256) void k_ifft_rows(
    const float2* __restrict__ temp, u16* __restrict__ cat2) {
  __shared__ __align__(16) float2 buf[4][2][256];
  __shared__ __align__(16) u16 slab[256 * 34];   // [x][c]
  const int tid = threadIdx.x, wv = tid >> 6, lane = tid & 63;
  const int bid = blockIdx.x;
  const int b = bid >> 8, y = bid & 255;

  for (int it = 0; it < 8; ++it) {
    const int c = it * 4 + wv;
    const float2* row = temp + ((size_t)(b * 32 + c) * 256 + y) * 132;
    float2 v0 = row[lane];
    float2 v1 = row[lane + 64];
    float2 vN = row[128];
    float2* X = &buf[wv][0][0];
    X[lane] = v0;
    X[lane + 64] = v1;
    X[192 - lane] = make_float2(v1.x, -v1.y);     // conj(X[64+lane])
    if (lane > 0) X[256 - lane] = make_float2(v0.x, -v0.y);  // conj(X[lane])
    else          X[128] = vN;
    __syncthreads();
    fft256<1>(X, &buf[wv][1][0], lane);
    const float inv = 1.0f / 65536.0f;
#pragma unroll
    for (int r = 0; r < 4; ++r) {
      int xc = lane + 64 * r;
      slab[xc * 34 + c] = f2bf(fabsf(X[xc].x * inv));
    }
    __syncthreads();
  }

  u16* dst = cat2 + (size_t)(b * 256 + y) * 256 * 32;
  const int px = tid;                       // one pixel per thread
  const u32* srow = (const u32*)(slab + px * 34);
  uint4 o0 = make_uint4(srow[0], srow[1], srow[2], srow[3]);
  uint4 o1 = make_uint4(srow[4], srow[5], srow[6], srow[7]);
  uint4 o2 = make_uint4(srow[8], srow[9], srow[10], srow[11]);
  uint4 o3 = make_uint4(srow[12], srow[13], srow[14], srow[15]);
  uint4* d4 = (uint4*)(dst + (size_t)px * 32);
  d4[0] = o0; d4[1] = o1; d4[2] = o2; d4[3] = o3;
}

// ---------------------------------------------------------------------------
// Kernel 5: 1x1 projection: out[px][d] = sum_c cat[c]*P[d][c] + Pb[d]
// v2: NO LDS. Weight rows are wave-uniform -> read directly from global
// (s_load into SGPRs; v_fma with SGPR operand). R5 showed this kernel was
// LDS-pipe-bound on 1024 uniform ds_read_b128 broadcasts per wave.
// ---------------------------------------------------------------------------
__global__ __launch_bounds__(256) void k_proj(
    const u16* __restrict__ cat1, const u16* __restrict__ cat2,
    const void* __restrict__ pjw, const void* __restrict__ pjb,
    void* __restrict__ outv, const u32* __restrict__ flag) {
  const int isbf = (int)*flag;
  const int tid = threadIdx.x;

  const size_t px = (size_t)blockIdx.x * 256 + tid;
  float xin[64];
  const uint4* r1 = (const uint4*)(cat1 + px * 32);
  const uint4* r2 = (const uint4*)(cat2 + px * 32);
#pragma unroll
  for (int g = 0; g < 4; ++g) {
    uint4 u = r1[g];
    xin[g*8+0] = lo16f(u.x); xin[g*8+1] = hi16f(u.x);
    xin[g*8+2] = lo16f(u.y); xin[g*8+3] = hi16f(u.y);
    xin[g*8+4] = lo16f(u.z); xin[g*8+5] = hi16f(u.z);
    xin[g*8+6] = lo16f(u.w); xin[g*8+7] = hi16f(u.w);
    uint4 v = r2[g];
    xin[32+g*8+0] = lo16f(v.x); xin[32+g*8+1] = hi16f(v.x);
    xin[32+g*8+2] = lo16f(v.y); xin[32+g*8+3] = hi16f(v.y);
    xin[32+g*8+4] = lo16f(v.z); xin[32+g*8+5] = hi16f(v.z);
    xin[32+g*8+6] = lo16f(v.w); xin[32+g*8+7] = hi16f(v.w);
  }

  float o[64];
#pragma unroll
  for (int d0 = 0; d0 < 64; d0 += 4) {
    float a0 = lds1(pjb, d0+0, isbf);
    float a1 = lds1(pjb, d0+1, isbf);
    float a2 = lds1(pjb, d0+2, isbf);
    float a3 = lds1(pjb, d0+3, isbf);
#pragma unroll
    for (int cb = 0; cb < 16; ++cb) {
      float4 w0 = ld4(pjw, (size_t)(d0+0) * 64 + cb * 4, isbf);
      float4 w1 = ld4(pjw, (size_t)(d0+1) * 64 + cb * 4, isbf);
      float4 w2 = ld4(pjw, (size_t)(d0+2) * 64 + cb * 4, isbf);
      float4 w3 = ld4(pjw, (size_t)(d0+3) * 64 + cb * 4, isbf);
      float x0 = xin[cb*4+0], x1 = xin[cb*4+1], x2 = xin[cb*4+2], x3 = xin[cb*4+3];
      a0 = fmaf(x0, w0.x, a0); a0 = fmaf(x1, w0.y, a0); a0 = fmaf(x2, w0.z, a0); a0 = fmaf(x3, w0.w, a0);
      a1 = fmaf(x0, w1.x, a1); a1 = fmaf(x1, w1.y, a1); a1 = fmaf(x2, w1.z, a1); a1 = fmaf(x3, w1.w, a1);
      a2 = fmaf(x0, w2.x, a2); a2 = fmaf(x1, w2.y, a2); a2 = fmaf(x2, w2.z, a2); a2 = fmaf(x3, w2.w, a2);
      a3 = fmaf(x0, w3.x, a3); a3 = fmaf(x1, w3.y, a3); a3 = fmaf(x2, w3.z, a3); a3 = fmaf(x3, w3.w, a3);
    }
    o[d0] = a0; o[d0+1] = a1; o[d0+2] = a2; o[d0+3] = a3;
  }

  if (isbf) {
    u16* op = (u16*)outv + px * 64;
#pragma unroll
    for (int g = 0; g < 8; ++g) {
      uint4 u;
      u.x = (u32)f2bf(o[g*8+0]) | ((u32)f2bf(o[g*8+1]) << 16);
      u.y = (u32)f2bf(o[g*8+2]) | ((u32)f2bf(o[g*8+3]) << 16);
      u.z = (u32)f2bf(o[g*8+4]) | ((u32)f2bf(o[g*8+5]) << 16);
      u.w = (u32)f2bf(o[g*8+6]) | ((u32)f2bf(o[g*8+7]) << 16);
      ((uint4*)op)[g] = u;
    }
  } else {
    float* op = (float*)outv + px * 64;
#pragma unroll
    for (int g = 0; g < 16; ++g) {
      ((float4*)op)[g] = make_float4(o[g*4+0], o[g*4+1], o[g*4+2], o[g*4+3]);
    }
  }
}

// ---------------------------------------------------------------------------
extern "C" void kernel_launch(void* const* d_in, const int* in_sizes, int n_in,
                              void* d_out, int out_size, void* d_ws, size_t ws_size,
                              hipStream_t stream) {
  const void* x    = d_in[0];
  const void* wqkv = d_in[1];
  const void* bqkv = d_in[2];
  const void* pos  = d_in[3];
  const void* aw   = d_in[4];
  const void* ab   = d_in[5];
  const void* pw   = d_in[6];
  const void* pb   = d_in[7];
  const void* pjw  = d_in[8];
  const void* pjb  = d_in[9];

  char* ws = (char*)d_ws;
  float2* temp = (float2*)ws;                                  // 69,206,016 B
  size_t tempBytes = (size_t)8 * 32 * 256 * 132 * sizeof(float2);
  u16* cat1 = (u16*)(ws + tempBytes);                          // 33,554,432 B
  u16* cat2 = cat1 + (size_t)8 * 256 * 256 * 32;               // 33,554,432 B
  u32* flag = (u32*)(ws + tempBytes + 2 * (size_t)8 * 256 * 256 * 32 * 2);

  k_detect<<<dim3(1), dim3(64), 0, stream>>>((const u16*)x, flag);
  k_attn<<<dim3(8192), dim3(256), 0, stream>>>(x, wqkv, bqkv, pos, cat1, flag);
  k_fft_rows<<<dim3(2048), dim3(256), 0, stream>>>(x, temp, flag);
  k_fft_cols<<<dim3(33 * 256), dim3(256), 0, stream>>>(temp, aw, ab, pw, pb, flag);
  k_ifft_rows<<<dim3(2048), dim3(256), 0, stream>>>(temp, cat2);
  k_proj<<<dim3(2048), dim3(256), 0, stream>>>(cat1, cat2, pjw, pjb, d_out, flag);
}

// Round 7
// 785.160 us; speedup vs baseline: 1.8617x; 1.8617x over previous
//
#include <hip/hip_runtime.h>
#include <hip/hip_bf16.h>
#include <math.h>

typedef unsigned short u16;
typedef unsigned int   u32;

#define PI_F 3.14159265358979323846f

__device__ __forceinline__ float bf2f(u16 u) {
  union { u32 i; float f; } v; v.i = ((u32)u) << 16; return v.f;
}
__device__ __forceinline__ u16 f2bf(float f) {
  union { float f; u32 i; } v; v.f = f;
  u32 x = v.i;
  return (u16)((x + 0x7fffu + ((x >> 16) & 1u)) >> 16);  // RNE
}
__device__ __forceinline__ float lo16f(u32 u) { return bf2f((u16)(u & 0xffffu)); }
__device__ __forceinline__ float hi16f(u32 u) { return bf2f((u16)(u >> 16)); }

// ---- dtype-agnostic input loads (isbf is wave-uniform) ---------------------
__device__ __forceinline__ float lds1(const void* p, size_t i, int isbf) {
  return isbf ? bf2f(((const u16*)p)[i]) : ((const float*)p)[i];
}
__device__ __forceinline__ float4 ld4(const void* p, size_t i, int isbf) {
  if (isbf) {
    uint2 u = *(const uint2*)((const u16*)p + i);
    return make_float4(lo16f(u.x), hi16f(u.x), lo16f(u.y), hi16f(u.y));
  }
  return *(const float4*)((const float*)p + i);
}
__device__ __forceinline__ void ld8(const void* p, size_t i, int isbf, float* dst) {
  if (isbf) {
    uint4 u = *(const uint4*)((const u16*)p + i);
    dst[0]=lo16f(u.x); dst[1]=hi16f(u.x); dst[2]=lo16f(u.y); dst[3]=hi16f(u.y);
    dst[4]=lo16f(u.z); dst[5]=hi16f(u.z); dst[6]=lo16f(u.w); dst[7]=hi16f(u.w);
  } else {
    float4 a = *(const float4*)((const float*)p + i);
    float4 b = *(const float4*)((const float*)p + i + 4);
    dst[0]=a.x; dst[1]=a.y; dst[2]=a.z; dst[3]=a.w;
    dst[4]=b.x; dst[5]=b.y; dst[6]=b.z; dst[7]=b.w;
  }
}

__device__ __forceinline__ float2 cmulf(float2 a, float c, float s) {
  return make_float2(a.x*c - a.y*s, a.x*s + a.y*c);
}

// ---------------------------------------------------------------------------
// Kernel 0: dtype detect. Even-indexed u16s of x: bf16 data -> exponent field
// is N(0,1)-plausible (~100%); float32 data -> low mantissa halves (~14%).
// ---------------------------------------------------------------------------
__global__ __launch_bounds__(64) void k_detect(const u16* __restrict__ x,
                                               u32* __restrict__ flag) {
  __shared__ int cnt[64];
  const int lane = threadIdx.x;
  int c = 0;
  for (int i = 0; i < 16; ++i) {
    u32 u = x[(size_t)(lane * 16 + i) * 1024];   // even u16 index, < 1.05M
    int e = (u >> 7) & 0xFF;
    c += (e >= 0x60 && e < 0x84) ? 1 : 0;
  }
  cnt[lane] = c;
  __syncthreads();
  if (lane == 0) {
    int s = 0;
    for (int i = 0; i < 64; ++i) s += cnt[i];
    *flag = (s > 512) ? 1u : 0u;
  }
}

// ---------------------------------------------------------------------------
// 256-point complex FFT, radix-4 Stockham, 64 lanes per FFT (lane = j).
// Data starts in b0, ends in b0 (4 stages, ping-pong). DIR=-1 fwd, +1 inv.
// ---------------------------------------------------------------------------
template<int DIR>
__device__ void fft256(float2* b0, float2* b1, int lane) {
  float2* src = b0;
  float2* dst = b1;
#pragma unroll
  for (int Ns = 1; Ns < 256; Ns *= 4) {
    int jm = lane & (Ns - 1);
    float ang = (float)DIR * (2.0f * PI_F) * (float)jm / (float)(Ns * 4);
    float2 v0 = src[lane];
    float2 v1 = src[lane + 64];
    float2 v2 = src[lane + 128];
    float2 v3 = src[lane + 192];
    float s1, c1;
    __sincosf(ang, &s1, &c1);
    float c2 = c1*c1 - s1*s1, s2 = 2.f*c1*s1;
    float c3 = c2*c1 - s2*s1, s3 = s2*c1 + c2*s1;
    v1 = cmulf(v1, c1, s1);
    v2 = cmulf(v2, c2, s2);
    v3 = cmulf(v3, c3, s3);
    float2 t0 = make_float2(v0.x + v2.x, v0.y + v2.y);
    float2 t1 = make_float2(v0.x - v2.x, v0.y - v2.y);
    float2 t2 = make_float2(v1.x + v3.x, v1.y + v3.y);
    float2 t3 = make_float2(v1.x - v3.x, v1.y - v3.y);
    float2 t3r = (DIR < 0) ? make_float2(t3.y, -t3.x) : make_float2(-t3.y, t3.x);
    int idxD = (lane / Ns) * (Ns * 4) + jm;
    dst[idxD]          = make_float2(t0.x + t2.x, t0.y + t2.y);
    dst[idxD + Ns]     = make_float2(t1.x + t3r.x, t1.y + t3r.y);
    dst[idxD + 2 * Ns] = make_float2(t0.x - t2.x, t0.y - t2.y);
    dst[idxD + 3 * Ns] = make_float2(t1.x - t3r.x, t1.y - t3r.y);
    float2* tmp = src; src = dst; dst = tmp;
    __syncthreads();
  }
}

// ---------------------------------------------------------------------------
// Kernel 1: window attention (local mixer). ONE BLOCK PER WINDOW.
// Thread = (head wv = tid>>6, token lane = tid&63). R5-verified version:
// weights staged in LDS (uniform ds_read broadcast is the fast path on
// gfx950 — R6 proved global re-fetch of uniform weights is 3x slower).
// Q/K/V in LDS qkv[96][64]; per-thread live set ~50 VGPR (spill-free).
// ---------------------------------------------------------------------------
__global__ __launch_bounds__(256) void k_attn(
    const void* __restrict__ x, const void* __restrict__ wqkv,
    const void* __restrict__ bqkv, const void* __restrict__ pos,
    u16* __restrict__ cat1, const u32* __restrict__ flag) {
  __shared__ __align__(16) float wl[96 * 32];     // 12 KB
  __shared__ float bl[96];
  __shared__ __align__(16) float qkv[96 * 64];    // 24 KB: row d, col token

  const int isbf = (int)*flag;
  const int tid = threadIdx.x;
  const int wv = tid >> 6;     // QKV phase: d-quarter; attn phase: head
  const int lane = tid & 63;   // token = i0*8+j0

  for (int i = tid; i < 96 * 32; i += 256) wl[i] = lds1(wqkv, i, isbf);
  if (tid < 96) bl[tid] = lds1(bqkv, tid, isbf);
  __syncthreads();

  const int w = blockIdx.x;    // window id 0..8191
  const int b = w >> 10;
  const int rem = w & 1023;
  const int by = rem >> 5, bx = rem & 31;
  const int i0 = lane >> 3, j0 = lane & 7;
  const int py = by * 8 + i0, px = bx * 8 + j0;

  // token's 32 input channels (first half of c=64)
  const size_t pixbase = ((size_t)((b * 256 + py) * 256 + px)) * 64;
  float xr[32];
#pragma unroll
  for (int g = 0; g < 4; ++g) ld8(x, pixbase + g * 8, isbf, xr + g * 8);

  // ---- QKV: wave wv computes output rows d in [wv*24, wv*24+24) ----------
#pragma unroll
  for (int dd0 = 0; dd0 < 24; dd0 += 8) {
    const int d0 = wv * 24 + dd0;
    float acc[8];
#pragma unroll
    for (int u = 0; u < 8; ++u) acc[u] = bl[d0 + u];
#pragma unroll
    for (int u = 0; u < 8; ++u) {
      const float4* wr = (const float4*)(wl + (d0 + u) * 32);  // uniform: bcast
#pragma unroll
      for (int cb = 0; cb < 8; ++cb) {
        float4 w4 = wr[cb];
        acc[u] = fmaf(xr[cb*4+0], w4.x, acc[u]);
        acc[u] = fmaf(xr[cb*4+1], w4.y, acc[u]);
        acc[u] = fmaf(xr[cb*4+2], w4.z, acc[u]);
        acc[u] = fmaf(xr[cb*4+3], w4.w, acc[u]);
      }
    }
#pragma unroll
    for (int u = 0; u < 8; ++u) qkv[(d0 + u) * 64 + lane] = acc[u];  // stride-1
  }
  __syncthreads();

  // ---- attention: this thread owns (head wv, query token lane) -----------
  float qv[8];
#pragma unroll
  for (int cc = 0; cc < 8; ++cc)
    qv[cc] = qkv[(wv * 8 + cc) * 64 + lane] * 0.35355339059327373f;
  const float* kt = qkv + (32 + wv * 8) * 64;   // k rows for this head
  const float* vt = qkv + (64 + wv * 8) * 64;   // v rows for this head

  float m = -1e30f, l = 0.f;
  float o[8];
#pragma unroll
  for (int cc = 0; cc < 8; ++cc) o[cc] = 0.f;
  const size_t prow = (size_t)(wv * 64 + lane) * 64;

#pragma unroll 1
  for (int jb = 0; jb < 16; ++jb) {
    float4 pp = ld4(pos, prow + jb * 4, isbf);
    float s0 = pp.x, s1 = pp.y, s2 = pp.z, s3 = pp.w;
#pragma unroll
    for (int cc = 0; cc < 8; ++cc) {
      float4 k4 = *(const float4*)(kt + cc * 64 + jb * 4);   // uniform: bcast
      float q1 = qv[cc];
      s0 = fmaf(q1, k4.x, s0); s1 = fmaf(q1, k4.y, s1);
      s2 = fmaf(q1, k4.z, s2); s3 = fmaf(q1, k4.w, s3);
    }
    float mn = fmaxf(fmaxf(fmaxf(s0, s1), fmaxf(s2, s3)), m);
    float fac = __expf(m - mn);
    float e0 = __expf(s0 - mn), e1 = __expf(s1 - mn);
    float e2 = __expf(s2 - mn), e3 = __expf(s3 - mn);
    l = l * fac + (e0 + e1 + e2 + e3);
#pragma unroll
    for (int cc = 0; cc < 8; ++cc) {
      float4 v4 = *(const float4*)(vt + cc * 64 + jb * 4);   // uniform: bcast
      float t = o[cc] * fac;
      t = fmaf(e0, v4.x, t); t = fmaf(e1, v4.y, t);
      t = fmaf(e2, v4.z, t); t = fmaf(e3, v4.w, t);
      o[cc] = t;
    }
    m = mn;
  }
  float rs = 1.f / l;

  // head wv owns channels wv*8..wv*8+7 of pixel (py,px): one 16B store
  u16* opix = cat1 + ((size_t)((b * 256 + py) * 256 + px)) * 32 + wv * 8;
  uint4 u;
  u.x = (u32)f2bf(o[0] * rs) | ((u32)f2bf(o[1] * rs) << 16);
  u.y = (u32)f2bf(o[2] * rs) | ((u32)f2bf(o[3] * rs) << 16);
  u.z = (u32)f2bf(o[4] * rs) | ((u32)f2bf(o[5] * rs) << 16);
  u.w = (u32)f2bf(o[6] * rs) | ((u32)f2bf(o[7] * rs) << 16);
  *(uint4*)opix = u;
}

// ---------------------------------------------------------------------------
// Kernel 2: forward row FFTs (along w). Block = one (b,y); wave per channel
// iter. temp layout: [b*32+c][y][132] float2, k=0..128 valid.
// ---------------------------------------------------------------------------
__global__ __launch_bounds__(256) void k_fft_rows(
    const void* __restrict__ x, float2* __restrict__ temp,
    const u32* __restrict__ flag) {
  __shared__ __align__(16) float2 buf[4][2][256];
  const int isbf = (int)*flag;
  const int tid = threadIdx.x, wv = tid >> 6, lane = tid & 63;
  const int bid = blockIdx.x;
  const int b = bid >> 8, y = bid & 255;
  const size_t rowbase = (size_t)(b * 256 + y) * 256 * 64;

  for (int it = 0; it < 8; ++it) {
    const int c = it * 4 + wv;
#pragma unroll
    for (int r = 0; r < 4; ++r) {
      int xc = lane + 64 * r;
      float v = lds1(x, rowbase + (size_t)xc * 64 + 32 + c, isbf);
      buf[wv][0][xc] = make_float2(v, 0.f);
    }
    __syncthreads();
    fft256<-1>(&buf[wv][0][0], &buf[wv][1][0], lane);
    float2* row = temp + ((size_t)(b * 32 + c) * 256 + y) * 132;
    row[lane]      = buf[wv][0][lane];
    row[lane + 64] = buf[wv][0][lane + 64];
    if (lane == 0) row[128] = buf[wv][0][128];
    __syncthreads();
  }
}

// ---------------------------------------------------------------------------
// Kernel 3: column FFT + amp/phase pointwise + inverse column FFT.
// Block = (plane p = b*32+c, tile of 4 kx columns). 33 tiles.
// ---------------------------------------------------------------------------
__global__ __launch_bounds__(256) void k_fft_cols(
    float2* __restrict__ temp,
    const void* __restrict__ aw, const void* __restrict__ ab,
    const void* __restrict__ pw, const void* __restrict__ pb,
    const u32* __restrict__ flag) {
  __shared__ __align__(16) float2 cb[4][2][256];
  const int isbf = (int)*flag;
  const int tid = threadIdx.x, wv = tid >> 6, lane = tid & 63;
  const int tile = blockIdx.x % 33;
  const int p = blockIdx.x / 33;
  const int c = p & 31;
  const int k0 = tile * 4;
  float2* plane = temp + (size_t)p * 256 * 132;

  {
    const int y = tid;
    const float4* src = (const float4*)(plane + (size_t)y * 132 + k0);
    float4 f0 = src[0], f1 = src[1];
    cb[0][0][y] = make_float2(f0.x, f0.y);
    cb[1][0][y] = make_float2(f0.z, f0.w);
    cb[2][0][y] = make_float2(f1.x, f1.y);
    cb[3][0][y] = make_float2(f1.z, f1.w);
  }
  __syncthreads();
  fft256<-1>(&cb[wv][0][0], &cb[wv][1][0], lane);

  const float awf = lds1(aw, c, isbf), abf = lds1(ab, c, isbf);
  const float pwf = lds1(pw, c, isbf), pbf = lds1(pb, c, isbf);
#pragma unroll
  for (int r = 0; r < 4; ++r) {
    float2 F = cb[wv][0][lane + 64 * r];
    float amp = sqrtf(F.x * F.x + F.y * F.y);
    float ph = atan2f(F.y, F.x);
    float a2 = amp * awf + abf;
    float p2 = ph * pwf + pbf;
    float sn, cs;
    __sincosf(p2, &sn, &cs);
    cb[wv][0][lane + 64 * r] = make_float2(a2 * cs + 2e-8f, a2 * sn + 1e-8f);
  }
  __syncthreads();
  fft256<1>(&cb[wv][0][0], &cb[wv][1][0], lane);
  // trailing barrier inside fft256 makes cross-wave reads below safe
  {
    const int y = tid;
    float4* dst = (float4*)(plane + (size_t)y * 132 + k0);
    float2 a0 = cb[0][0][y], a1 = cb[1][0][y], a2 = cb[2][0][y], a3 = cb[3][0][y];
    dst[0] = make_float4(a0.x, a0.y, a1.x, a1.y);
    dst[1] = make_float4(a2.x, a2.y, a3.x, a3.y);
  }
}

// ---------------------------------------------------------------------------
// Kernel 4: inverse row FFTs (Hermitian reconstruct), *1/65536, abs,
// write x2 bf16 to cat2 [b,y,x,32] via LDS slab (coalesced).
// ---------------------------------------------------------------------------
__global__ __launch_bounds__(256) void k_ifft_rows(
    const float2* __restrict__ temp, u16* __restrict__ cat2) {
  __shared__ __align__(16) float2 buf[4][2][256];
  __shared__ __align__(16) u16 slab[256 * 34];   // [x][c]
  const int tid = threadIdx.x, wv = tid >> 6, lane = tid & 63;
  const int bid = blockIdx.x;
  const int b = bid >> 8, y = bid & 255;

  for (int it = 0; it < 8; ++it) {
    const int c = it * 4 + wv;
    const float2* row = temp + ((size_t)(b * 32 + c) * 256 + y) * 132;
    float2 v0 = row[lane];
    float2 v1 = row[lane + 64];
    float2 vN = row[128];
    float2* X = &buf[wv][0][0];
    X[lane] = v0;
    X[lane + 64] = v1;
    X[192 - lane] = make_float2(v1.x, -v1.y);     // conj(X[64+lane])
    if (lane > 0) X[256 - lane] = make_float2(v0.x, -v0.y);  // conj(X[lane])
    else          X[128] = vN;
    __syncthreads();
    fft256<1>(X, &buf[wv][1][0], lane);
    const float inv = 1.0f / 65536.0f;
#pragma unroll
    for (int r = 0; r < 4; ++r) {
      int xc = lane + 64 * r;
      slab[xc * 34 + c] = f2bf(fabsf(X[xc].x * inv));
    }
    __syncthreads();
  }

  u16* dst = cat2 + (size_t)(b * 256 + y) * 256 * 32;
  const int px = tid;                       // one pixel per thread
  const u32* srow = (const u32*)(slab + px * 34);
  uint4 o0 = make_uint4(srow[0], srow[1], srow[2], srow[3]);
  uint4 o1 = make_uint4(srow[4], srow[5], srow[6], srow[7]);
  uint4 o2 = make_uint4(srow[8], srow[9], srow[10], srow[11]);
  uint4 o3 = make_uint4(srow[12], srow[13], srow[14], srow[15]);
  uint4* d4 = (uint4*)(dst + (size_t)px * 32);
  d4[0] = o0; d4[1] = o1; d4[2] = o2; d4[3] = o3;
}

// ---------------------------------------------------------------------------
// Kernel 5: 1x1 projection. v3: register-blocked M=2 pixels per thread.
// R5 version was LDS-issue-bound (1024 uniform ds_read_b128 per wave for 64
// pixels). Processing 2 pixels/thread amortizes each weight broadcast over
// 8 FMAs -> 8 b128/pixel. xin kept bf16-PACKED (u32[32] per pixel, 64 VGPR
// for both) and unpacked on the fly with compile-time indices (rule #20).
// Outputs stored per 8-channel d-block directly (no o[64] array).
// Per-output FMA order identical to R5 -> bit-identical results.
// ---------------------------------------------------------------------------
__global__ __launch_bounds__(256) void k_proj(
    const u16* __restrict__ cat1, const u16* __restrict__ cat2,
    const void* __restrict__ pjw, const void* __restrict__ pjb,
    void* __restrict__ outv, const u32* __restrict__ flag) {
  __shared__ __align__(16) float P[64 * 64];
  __shared__ float Pb[64];
  const int isbf = (int)*flag;
  const int tid = threadIdx.x;
#pragma unroll
  for (int i = 0; i < 16; ++i) P[tid + 256 * i] = lds1(pjw, tid + 256 * i, isbf);
  if (tid < 64) Pb[tid] = lds1(pjb, tid, isbf);
  __syncthreads();

  const size_t px0 = (size_t)blockIdx.x * 512 + tid;   // pixels px0, px0+256
  const size_t px1 = px0 + 256;

  // packed activations: [0..15]=cat1, [16..31]=cat2 (u32 = 2 bf16)
  u32 xp0[32], xp1[32];
  {
    const uint4* a1 = (const uint4*)(cat1 + px0 * 32);
    const uint4* a2 = (const uint4*)(cat2 + px0 * 32);
    const uint4* b1 = (const uint4*)(cat1 + px1 * 32);
    const uint4* b2 = (const uint4*)(cat2 + px1 * 32);
#pragma unroll
    for (int g = 0; g < 4; ++g) {
      uint4 u = a1[g];
      xp0[g*4+0]=u.x; xp0[g*4+1]=u.y; xp0[g*4+2]=u.z; xp0[g*4+3]=u.w;
      uint4 v = a2[g];
      xp0[16+g*4+0]=v.x; xp0[16+g*4+1]=v.y; xp0[16+g*4+2]=v.z; xp0[16+g*4+3]=v.w;
      uint4 s = b1[g];
      xp1[g*4+0]=s.x; xp1[g*4+1]=s.y; xp1[g*4+2]=s.z; xp1[g*4+3]=s.w;
      uint4 t = b2[g];
      xp1[16+g*4+0]=t.x; xp1[16+g*4+1]=t.y; xp1[16+g*4+2]=t.z; xp1[16+g*4+3]=t.w;
    }
  }

#pragma unroll 1
  for (int d0 = 0; d0 < 64; d0 += 8) {
    float acc0[8], acc1[8];
#pragma unroll
    for (int u = 0; u < 8; ++u) { acc0[u] = Pb[d0 + u]; acc1[u] = acc0[u]; }
#pragma unroll
    for (int cb = 0; cb < 16; ++cb) {
      float x0[4], x1[4];
#pragma unroll
      for (int j = 0; j < 4; ++j) {
        const int c = cb * 4 + j;            // compile-time after unroll
        const u32 ua = xp0[c >> 1], ub = xp1[c >> 1];
        x0[j] = (c & 1) ? hi16f(ua) : lo16f(ua);
        x1[j] = (c & 1) ? hi16f(ub) : lo16f(ub);
      }
#pragma unroll
      for (int u = 0; u < 8; ++u) {
        float4 w4 = *(const float4*)(P + (d0 + u) * 64 + cb * 4);  // bcast
        float a = acc0[u];
        a = fmaf(x0[0], w4.x, a); a = fmaf(x0[1], w4.y, a);
        a = fmaf(x0[2], w4.z, a); a = fmaf(x0[3], w4.w, a);
        acc0[u] = a;
        float b = acc1[u];
        b = fmaf(x1[0], w4.x, b); b = fmaf(x1[1], w4.y, b);
        b = fmaf(x1[2], w4.z, b); b = fmaf(x1[3], w4.w, b);
        acc1[u] = b;
      }
    }
    if (isbf) {
      uint4 u;
      u.x = (u32)f2bf(acc0[0]) | ((u32)f2bf(acc0[1]) << 16);
      u.y = (u32)f2bf(acc0[2]) | ((u32)f2bf(acc0[3]) << 16);
      u.z = (u32)f2bf(acc0[4]) | ((u32)f2bf(acc0[5]) << 16);
      u.w = (u32)f2bf(acc0[6]) | ((u32)f2bf(acc0[7]) << 16);
      *(uint4*)((u16*)outv + px0 * 64 + d0) = u;
      uint4 v;
      v.x = (u32)f2bf(acc1[0]) | ((u32)f2bf(acc1[1]) << 16);
      v.y = (u32)f2bf(acc1[2]) | ((u32)f2bf(acc1[3]) << 16);
      v.z = (u32)f2bf(acc1[4]) | ((u32)f2bf(acc1[5]) << 16);
      v.w = (u32)f2bf(acc1[6]) | ((u32)f2bf(acc1[7]) << 16);
      *(uint4*)((u16*)outv + px1 * 64 + d0) = v;
    } else {
      float* op0 = (float*)outv + px0 * 64 + d0;
      ((float4*)op0)[0] = make_float4(acc0[0], acc0[1], acc0[2], acc0[3]);
      ((float4*)op0)[1] = make_float4(acc0[4], acc0[5], acc0[6], acc0[7]);
      float* op1 = (float*)outv + px1 * 64 + d0;
      ((float4*)op1)[0] = make_float4(acc1[0], acc1[1], acc1[2], acc1[3]);
      ((float4*)op1)[1] = make_float4(acc1[4], acc1[5], acc1[6], acc1[7]);
    }
  }
}

// ---------------------------------------------------------------------------
extern "C" void kernel_launch(void* const* d_in, const int* in_sizes, int n_in,
                              void* d_out, int out_size, void* d_ws, size_t ws_size,
                              hipStream_t stream) {
  const void* x    = d_in[0];
  const void* wqkv = d_in[1];
  const void* bqkv = d_in[2];
  const void* pos  = d_in[3];
  const void* aw   = d_in[4];
  const void* ab   = d_in[5];
  const void* pw   = d_in[6];
  const void* pb   = d_in[7];
  const void* pjw  = d_in[8];
  const void* pjb  = d_in[9];

  char* ws = (char*)d_ws;
  float2* temp = (float2*)ws;                                  // 69,206,016 B
  size_t tempBytes = (size_t)8 * 32 * 256 * 132 * sizeof(float2);
  u16* cat1 = (u16*)(ws + tempBytes);                          // 33,554,432 B
  u16* cat2 = cat1 + (size_t)8 * 256 * 256 * 32;               // 33,554,432 B
  u32* flag = (u32*)(ws + tempBytes + 2 * (size_t)8 * 256 * 256 * 32 * 2);

  k_detect<<<dim3(1), dim3(64), 0, stream>>>((const u16*)x, flag);
  k_attn<<<dim3(8192), dim3(256), 0, stream>>>(x, wqkv, bqkv, pos, cat1, flag);
  k_fft_rows<<<dim3(2048), dim3(256), 0, stream>>>(x, temp, flag);
  k_fft_cols<<<dim3(33 * 256), dim3(256), 0, stream>>>(temp, aw, ab, pw, pb, flag);
  k_ifft_rows<<<dim3(2048), dim3(256), 0, stream>>>(temp, cat2);
  k_proj<<<dim3(1024), dim3(256), 0, stream>>>(cat1, cat2, pjw, pjb, d_out, flag);
}